// Round 4
// baseline (243.324 us; speedup 1.0000x reference)
//
#include <hip/hip_runtime.h>
#include <stdint.h>

// FMFMNeuron LIF scan, 3-phase:
//  1) compress: 134MB f32 spikes -> 4MB of 2-bit cur-codes [T/16][B] u32
//     (massively parallel, HBM-BW-bound)
//  2) scan: 64 waves read 4MB codes (L2-resident), run the exact sequential
//     recurrence (chain-latency-bound, no HBM pressure), emit 1-bit spikes
//  3) expand: 2MB bits -> 67MB f32 output (write-BW-bound, proven)
//
// Exactness: spikes in {0,1} so cur has exactly 4 possible f32 values,
// precomputed with the same __fmul_rn/__fadd_rn as round-1's validated code:
//   code 0 -> 0.0f, 1 -> fmul(1,w1)=w1, 2 -> w2, 3 -> fadd(w1,w2)
// mem update unchanged (strict left-to-right, no FMA):
//   m = fsub(fadd(fmul(0.95f,mem), cur), rst);  spk = m > 1.0f; rst' = spk

#define T_STEPS 4096
#define B_NEUR  4096
#define KG      (T_STEPS / 16)   // 256 code words per neuron
#define NWORDS  (T_STEPS / 32)   // 128 packed spike words per neuron

// ---- phase 1: compress spikes to 2-bit codes -------------------------------
__global__ __launch_bounds__(256) void fmfm_compress(
    const float2* __restrict__ sp,     // [T][B] float2
    uint32_t*     __restrict__ codes)  // [T/16][B]
{
    const int tid = blockIdx.x * 256 + threadIdx.x;  // 0 .. 1M-1
    const int b   = tid & (B_NEUR - 1);
    const int kg  = tid >> 12;                       // 0..255
    const float2* p = sp + (size_t)kg * 16 * B_NEUR + b;
    uint32_t w = 0;
    #pragma unroll
    for (int i = 0; i < 16; ++i) {
        float2 s = p[(size_t)i * B_NEUR];
        uint32_t c = (s.x != 0.0f ? 1u : 0u) | (s.y != 0.0f ? 2u : 0u);
        w |= c << (2 * i);
    }
    codes[(size_t)kg * B_NEUR + b] = w;
}

// ---- phase 2: sequential scan over compressed codes ------------------------
__global__ __launch_bounds__(64) void fmfm_scan_codes(
    const uint32_t* __restrict__ codes,   // [T/16][B]
    const float*    __restrict__ W,       // [w1, w2]
    uint32_t*       __restrict__ bits_out)// [T/32][B]
{
    const int b = blockIdx.x * 64 + threadIdx.x;
    const float w1  = W[0];
    const float w2  = W[1];
    const float w12 = __fadd_rn(w1, w2);   // same rounding as fadd(fmul..) path

    const uint32_t* cp = codes + b;

    float mem = 0.0f;
    float rst = 0.0f;

    uint32_t w_cur = cp[0];
    uint32_t bits  = 0;

    for (int kg = 0; kg < KG; ++kg) {
        uint32_t w_next = (kg + 1 < KG) ? cp[(size_t)(kg + 1) * B_NEUR] : 0u;
        uint32_t w = w_cur;
        #pragma unroll
        for (int i = 0; i < 16; ++i) {
            uint32_t c = (w >> (2 * i)) & 3u;
            // static selects, off the critical chain
            float cur = (c & 1u) ? ((c & 2u) ? w12 : w1)
                                 : ((c & 2u) ? w2  : 0.0f);
            float m = __fsub_rn(__fadd_rn(__fmul_rn(0.95f, mem), cur), rst);
            uint32_t sb = (m > 1.0f) ? 1u : 0u;
            bits |= sb << (((kg & 1) << 4) + i);
            rst = sb ? 1.0f : 0.0f;
            mem = m;
        }
        if (kg & 1) {
            bits_out[(size_t)(kg >> 1) * B_NEUR + b] = bits;
            bits = 0;
        }
        w_cur = w_next;
    }
}

// ---- phase 3: expand bits to f32 (proven in round 3) -----------------------
__global__ __launch_bounds__(256) void fmfm_expand(
    const uint32_t* __restrict__ bits,  // [T/32][B]
    float*          __restrict__ out)   // [T][B]
{
    const int tid = blockIdx.x * 256 + threadIdx.x;  // 0..131071
    const int b4  = tid & 1023;
    const int w   = tid >> 10;
    const uint4 wv = *reinterpret_cast<const uint4*>(
        bits + (size_t)w * B_NEUR + (size_t)b4 * 4);
    float4* o = reinterpret_cast<float4*>(
        out + (size_t)w * 32 * B_NEUR + (size_t)b4 * 4);
    #pragma unroll
    for (int j = 0; j < 32; ++j) {
        float4 v;
        v.x = ((wv.x >> j) & 1u) ? 1.0f : 0.0f;
        v.y = ((wv.y >> j) & 1u) ? 1.0f : 0.0f;
        v.z = ((wv.z >> j) & 1u) ? 1.0f : 0.0f;
        v.w = ((wv.w >> j) & 1u) ? 1.0f : 0.0f;
        o[(size_t)j * (B_NEUR / 4)] = v;
    }
}

// ---- fallback: round-1 proven fused kernel (if ws too small) ---------------
__global__ __launch_bounds__(64) void fmfm_scan_fused(
    const float2* __restrict__ sp, const float* __restrict__ W,
    float* __restrict__ out)
{
    const int b = blockIdx.x * 64 + threadIdx.x;
    const float w1 = W[0];
    const float w2 = W[1];
    const float2* p = sp + b;
    float* q = out + b;
    float mem = 0.0f, rst = 0.0f;
    #pragma unroll 8
    for (int t = 0; t < T_STEPS; ++t) {
        float2 s = p[(size_t)t * B_NEUR];
        float cur = __fadd_rn(__fmul_rn(s.x, w1), __fmul_rn(s.y, w2));
        float m = __fsub_rn(__fadd_rn(__fmul_rn(0.95f, mem), cur), rst);
        float spk = (m > 1.0f) ? 1.0f : 0.0f;
        q[(size_t)t * B_NEUR] = spk;
        mem = m;
        rst = spk;
    }
}

extern "C" void kernel_launch(void* const* d_in, const int* in_sizes, int n_in,
                              void* d_out, int out_size, void* d_ws, size_t ws_size,
                              hipStream_t stream) {
    const float2* sp  = (const float2*)d_in[0];
    const float*  W   = (const float*)d_in[1];
    float*        out = (float*)d_out;

    const size_t codes_bytes = (size_t)KG * B_NEUR * sizeof(uint32_t);     // 4MB
    const size_t bits_bytes  = (size_t)NWORDS * B_NEUR * sizeof(uint32_t); // 2MB
    if (ws_size < codes_bytes + bits_bytes) {
        fmfm_scan_fused<<<dim3(B_NEUR / 64), dim3(64), 0, stream>>>(sp, W, out);
        return;
    }
    uint32_t* codes = (uint32_t*)d_ws;
    uint32_t* bits  = (uint32_t*)((char*)d_ws + codes_bytes);

    fmfm_compress<<<dim3(KG * B_NEUR / 256), dim3(256), 0, stream>>>(sp, codes);
    fmfm_scan_codes<<<dim3(B_NEUR / 64), dim3(64), 0, stream>>>(codes, W, bits);
    fmfm_expand<<<dim3(NWORDS * (B_NEUR / 4) / 256), dim3(256), 0, stream>>>(bits, out);
}

// Round 5
// 137.982 us; speedup vs baseline: 1.7635x; 1.7635x over previous
//
#include <hip/hip_runtime.h>
#include <stdint.h>

// FMFMNeuron LIF scan, 3-phase:
//  1) compress: 134MB f32 spikes -> 4MB of 2-bit cur-codes [T/16][B] u32
//  2) scan: 64 waves over codes; 4-word rotating prefetch + per-word
//     pre-decoded curs[16] so the 12cy/step dependence chain is the only cost
//  3) expand: 2MB spike bits -> 67MB f32 output
//
// Exactness (validated absmax=0 in rounds 1/3/4): spikes in {0,1} =>
//   cur in {0, w1, w2, fadd(w1,w2)} exactly; mem update strict left-to-right:
//   m = fsub(fadd(fmul(0.95f,mem), cur), rst); spk = m > 1.0f; rst' = spk.

#define T_STEPS 4096
#define B_NEUR  4096
#define KG      (T_STEPS / 16)   // 256 code words per neuron
#define NWORDS  (T_STEPS / 32)   // 128 packed spike words per neuron

// ---- phase 1: compress spikes to 2-bit codes -------------------------------
__global__ __launch_bounds__(256) void fmfm_compress(
    const float2* __restrict__ sp,     // [T][B] float2
    uint32_t*     __restrict__ codes)  // [T/16][B]
{
    const int tid = blockIdx.x * 256 + threadIdx.x;  // 0 .. 1M-1
    const int b   = tid & (B_NEUR - 1);
    const int kg  = tid >> 12;                       // 0..255
    const float2* p = sp + (size_t)kg * 16 * B_NEUR + b;
    uint32_t w = 0;
    #pragma unroll
    for (int i = 0; i < 16; ++i) {
        float2 s = p[(size_t)i * B_NEUR];
        uint32_t c = (s.x != 0.0f ? 1u : 0u) | (s.y != 0.0f ? 2u : 0u);
        w |= c << (2 * i);
    }
    codes[(size_t)kg * B_NEUR + b] = w;
}

// ---- phase 2: sequential scan over compressed codes ------------------------
__global__ __launch_bounds__(64) void fmfm_scan_codes(
    const uint32_t* __restrict__ codes,   // [T/16][B]
    const float*    __restrict__ W,       // [w1, w2]
    uint32_t*       __restrict__ bits_out)// [T/32][B]
{
    const int b = blockIdx.x * 64 + threadIdx.x;
    const float w1  = W[0];
    const float w2  = W[1];
    const float w12 = __fadd_rn(w1, w2);

    const uint32_t* cp = codes + b;

    float mem = 0.0f;
    float rst = 0.0f;
    uint32_t bits = 0;

#define STEPX(CUR, BITPOS)                                                \
    {                                                                     \
        float _m = __fsub_rn(__fadd_rn(__fmul_rn(0.95f, mem), (CUR)),     \
                             rst);                                        \
        uint32_t _sb = (_m > 1.0f) ? 1u : 0u;                             \
        bits |= _sb << (BITPOS);                                          \
        rst = _sb ? 1.0f : 0.0f;                                          \
        mem = _m;                                                         \
    }

#define PROCW(WORD, HALF)                                                 \
    {                                                                     \
        float _curs[16];                                                  \
        _Pragma("unroll")                                                 \
        for (int _i = 0; _i < 16; ++_i) {                                 \
            uint32_t _c = ((WORD) >> (2 * _i)) & 3u;                      \
            _curs[_i] = (_c & 1u) ? ((_c & 2u) ? w12 : w1)                \
                                  : ((_c & 2u) ? w2 : 0.0f);              \
        }                                                                 \
        _Pragma("unroll")                                                 \
        for (int _i = 0; _i < 16; ++_i)                                   \
            STEPX(_curs[_i], (((HALF) << 4) + _i))                        \
    }

    // 4-word rotating prefetch: wa..wd hold words kg..kg+3.
    uint32_t wa = cp[0];
    uint32_t wb = cp[(size_t)1 * B_NEUR];
    uint32_t wc = cp[(size_t)2 * B_NEUR];
    uint32_t wd = cp[(size_t)3 * B_NEUR];

    for (int kg = 0; kg < KG; kg += 4) {
        // issue next-4 loads now; consumed after 64 steps (~770cy of work)
        const int n0 = (kg + 4 < KG) ? kg + 4 : KG - 1;
        const int n1 = (kg + 5 < KG) ? kg + 5 : KG - 1;
        const int n2 = (kg + 6 < KG) ? kg + 6 : KG - 1;
        const int n3 = (kg + 7 < KG) ? kg + 7 : KG - 1;
        uint32_t ta = cp[(size_t)n0 * B_NEUR];
        uint32_t tb = cp[(size_t)n1 * B_NEUR];
        uint32_t tc = cp[(size_t)n2 * B_NEUR];
        uint32_t td = cp[(size_t)n3 * B_NEUR];

        PROCW(wa, 0)
        PROCW(wb, 1)
        bits_out[(size_t)(kg >> 1) * B_NEUR + b] = bits;
        bits = 0;
        PROCW(wc, 0)
        PROCW(wd, 1)
        bits_out[(size_t)((kg >> 1) + 1) * B_NEUR + b] = bits;
        bits = 0;

        wa = ta; wb = tb; wc = tc; wd = td;
    }
#undef STEPX
#undef PROCW
}

// ---- phase 3: expand bits to f32 (proven) ----------------------------------
__global__ __launch_bounds__(256) void fmfm_expand(
    const uint32_t* __restrict__ bits,  // [T/32][B]
    float*          __restrict__ out)   // [T][B]
{
    const int tid = blockIdx.x * 256 + threadIdx.x;  // 0..131071
    const int b4  = tid & 1023;
    const int w   = tid >> 10;
    const uint4 wv = *reinterpret_cast<const uint4*>(
        bits + (size_t)w * B_NEUR + (size_t)b4 * 4);
    float4* o = reinterpret_cast<float4*>(
        out + (size_t)w * 32 * B_NEUR + (size_t)b4 * 4);
    #pragma unroll
    for (int j = 0; j < 32; ++j) {
        float4 v;
        v.x = ((wv.x >> j) & 1u) ? 1.0f : 0.0f;
        v.y = ((wv.y >> j) & 1u) ? 1.0f : 0.0f;
        v.z = ((wv.z >> j) & 1u) ? 1.0f : 0.0f;
        v.w = ((wv.w >> j) & 1u) ? 1.0f : 0.0f;
        o[(size_t)j * (B_NEUR / 4)] = v;
    }
}

// ---- fallback: round-1 proven fused kernel (if ws too small) ---------------
__global__ __launch_bounds__(64) void fmfm_scan_fused(
    const float2* __restrict__ sp, const float* __restrict__ W,
    float* __restrict__ out)
{
    const int b = blockIdx.x * 64 + threadIdx.x;
    const float w1 = W[0];
    const float w2 = W[1];
    const float2* p = sp + b;
    float* q = out + b;
    float mem = 0.0f, rst = 0.0f;
    #pragma unroll 8
    for (int t = 0; t < T_STEPS; ++t) {
        float2 s = p[(size_t)t * B_NEUR];
        float cur = __fadd_rn(__fmul_rn(s.x, w1), __fmul_rn(s.y, w2));
        float m = __fsub_rn(__fadd_rn(__fmul_rn(0.95f, mem), cur), rst);
        float spk = (m > 1.0f) ? 1.0f : 0.0f;
        q[(size_t)t * B_NEUR] = spk;
        mem = m;
        rst = spk;
    }
}

extern "C" void kernel_launch(void* const* d_in, const int* in_sizes, int n_in,
                              void* d_out, int out_size, void* d_ws, size_t ws_size,
                              hipStream_t stream) {
    const float2* sp  = (const float2*)d_in[0];
    const float*  W   = (const float*)d_in[1];
    float*        out = (float*)d_out;

    const size_t codes_bytes = (size_t)KG * B_NEUR * sizeof(uint32_t);     // 4MB
    const size_t bits_bytes  = (size_t)NWORDS * B_NEUR * sizeof(uint32_t); // 2MB
    if (ws_size < codes_bytes + bits_bytes) {
        fmfm_scan_fused<<<dim3(B_NEUR / 64), dim3(64), 0, stream>>>(sp, W, out);
        return;
    }
    uint32_t* codes = (uint32_t*)d_ws;
    uint32_t* bits  = (uint32_t*)((char*)d_ws + codes_bytes);

    fmfm_compress<<<dim3(KG * B_NEUR / 256), dim3(256), 0, stream>>>(sp, codes);
    fmfm_scan_codes<<<dim3(B_NEUR / 64), dim3(64), 0, stream>>>(codes, W, bits);
    fmfm_expand<<<dim3(NWORDS * (B_NEUR / 4) / 256), dim3(256), 0, stream>>>(bits, out);
}

// Round 6
// 96.633 us; speedup vs baseline: 2.5180x; 1.4279x over previous
//
#include <hip/hip_runtime.h>
#include <stdint.h>

// FMFMNeuron LIF scan, 3-phase:
//  1) compress: 134MB f32 spikes -> 4MB of 2-bit cur-codes [T/16][B] u32
//  2) scan: 64 waves; 4-word global prefetch + LDS-LUT byte decode
//     (float4 per code byte) pipelined 1 word ahead. ~8 VALU/step.
//  3) expand: 2MB spike bits -> 67MB f32 output
//
// Exactness (absmax=0 through rounds 1/3/4/5): spikes in {0,1} =>
//   cur in {0, w1, w2, fadd(w1,w2)} exactly; mem update strict left-to-right:
//   m = fsub(fadd(fmul(0.95f,mem), cur), rst); spk = m > 1.0f; rst' = spk.
// LUT holds exactly those 4 float values -> decode is bit-identical.

#define T_STEPS 4096
#define B_NEUR  4096
#define KG      (T_STEPS / 16)   // 256 code words per neuron
#define NWORDS  (T_STEPS / 32)   // 128 packed spike words per neuron

// ---- phase 1: compress spikes to 2-bit codes -------------------------------
__global__ __launch_bounds__(256) void fmfm_compress(
    const float2* __restrict__ sp,     // [T][B] float2
    uint32_t*     __restrict__ codes)  // [T/16][B]
{
    const int tid = blockIdx.x * 256 + threadIdx.x;  // 0 .. 1M-1
    const int b   = tid & (B_NEUR - 1);
    const int kg  = tid >> 12;                       // 0..255
    const float2* p = sp + (size_t)kg * 16 * B_NEUR + b;
    uint32_t w = 0;
    #pragma unroll
    for (int i = 0; i < 16; ++i) {
        float2 s = p[(size_t)i * B_NEUR];
        uint32_t c = (s.x != 0.0f ? 1u : 0u) | (s.y != 0.0f ? 2u : 0u);
        w |= c << (2 * i);
    }
    codes[(size_t)kg * B_NEUR + b] = w;
}

// ---- phase 2: sequential scan over compressed codes ------------------------
__global__ __launch_bounds__(64) void fmfm_scan_codes(
    const uint32_t* __restrict__ codes,   // [T/16][B]
    const float*    __restrict__ W,       // [w1, w2]
    uint32_t*       __restrict__ bits_out)// [T/32][B]
{
    __shared__ float4 lut[256];   // per code byte: 4 exact cur values

    const int b = blockIdx.x * 64 + threadIdx.x;
    const float w1  = W[0];
    const float w2  = W[1];
    const float w12 = __fadd_rn(w1, w2);

#define LUTV(C) ((C) == 0u ? 0.0f : ((C) == 1u ? w1 : ((C) == 2u ? w2 : w12)))
    for (int e = threadIdx.x; e < 256; e += 64) {
        float4 v;
        v.x = LUTV((uint32_t)(e)      & 3u);
        v.y = LUTV((uint32_t)(e >> 2) & 3u);
        v.z = LUTV((uint32_t)(e >> 4) & 3u);
        v.w = LUTV((uint32_t)(e >> 6) & 3u);
        lut[e] = v;
    }
    __syncthreads();
#undef LUTV

    const uint32_t* cp = codes + b;
    float mem = 0.0f;
    float rst = 0.0f;
    uint32_t bits = 0;

#define STEP1(CUR, POS)                                                   \
    {                                                                     \
        float _m = __fsub_rn(__fadd_rn(__fmul_rn(0.95f, mem), (CUR)),     \
                             rst);                                        \
        uint32_t _sb = (_m > 1.0f) ? 1u : 0u;                             \
        bits |= _sb << (POS);                                             \
        rst = _sb ? 1.0f : 0.0f;                                          \
        mem = _m;                                                         \
    }

#define STEP16(Q0, Q1, Q2, Q3, BASE)                                      \
    STEP1(Q0.x, (BASE) + 0)  STEP1(Q0.y, (BASE) + 1)                      \
    STEP1(Q0.z, (BASE) + 2)  STEP1(Q0.w, (BASE) + 3)                      \
    STEP1(Q1.x, (BASE) + 4)  STEP1(Q1.y, (BASE) + 5)                      \
    STEP1(Q1.z, (BASE) + 6)  STEP1(Q1.w, (BASE) + 7)                      \
    STEP1(Q2.x, (BASE) + 8)  STEP1(Q2.y, (BASE) + 9)                      \
    STEP1(Q2.z, (BASE) + 10) STEP1(Q2.w, (BASE) + 11)                     \
    STEP1(Q3.x, (BASE) + 12) STEP1(Q3.y, (BASE) + 13)                     \
    STEP1(Q3.z, (BASE) + 14) STEP1(Q3.w, (BASE) + 15)

#define DECODE(WORD)                                                      \
    {                                                                     \
        n0 = lut[(WORD) & 0xffu];                                         \
        n1 = lut[((WORD) >> 8) & 0xffu];                                  \
        n2 = lut[((WORD) >> 16) & 0xffu];                                 \
        n3 = lut[(WORD) >> 24];                                           \
    }

    // 4-word global prefetch (wa..wd = words kg..kg+3); LUT decode runs one
    // word ahead (n* holds the NEXT word's curs while c* is being consumed).
    uint32_t wa = cp[0];
    uint32_t wb = cp[(size_t)1 * B_NEUR];
    uint32_t wc = cp[(size_t)2 * B_NEUR];
    uint32_t wd = cp[(size_t)3 * B_NEUR];

    float4 c0, c1, c2, c3, n0, n1, n2, n3;
    DECODE(wa)
    c0 = n0; c1 = n1; c2 = n2; c3 = n3;

    for (int kg = 0; kg < KG; kg += 4) {
        const int i0 = (kg + 4 < KG) ? kg + 4 : KG - 1;
        const int i1 = (kg + 5 < KG) ? kg + 5 : KG - 1;
        const int i2 = (kg + 6 < KG) ? kg + 6 : KG - 1;
        const int i3 = (kg + 7 < KG) ? kg + 7 : KG - 1;
        uint32_t ta = cp[(size_t)i0 * B_NEUR];
        uint32_t tb = cp[(size_t)i1 * B_NEUR];
        uint32_t tc = cp[(size_t)i2 * B_NEUR];
        uint32_t td = cp[(size_t)i3 * B_NEUR];

        DECODE(wb)
        STEP16(c0, c1, c2, c3, 0)
        c0 = n0; c1 = n1; c2 = n2; c3 = n3;

        DECODE(wc)
        STEP16(c0, c1, c2, c3, 16)
        bits_out[(size_t)(kg >> 1) * B_NEUR + b] = bits;
        bits = 0;
        c0 = n0; c1 = n1; c2 = n2; c3 = n3;

        DECODE(wd)
        STEP16(c0, c1, c2, c3, 0)
        c0 = n0; c1 = n1; c2 = n2; c3 = n3;

        DECODE(ta)   // ta loaded this iter; 48 steps elapsed cover latency
        STEP16(c0, c1, c2, c3, 16)
        bits_out[(size_t)((kg >> 1) + 1) * B_NEUR + b] = bits;
        bits = 0;
        c0 = n0; c1 = n1; c2 = n2; c3 = n3;

        wa = ta; wb = tb; wc = tc; wd = td;
    }
#undef STEP1
#undef STEP16
#undef DECODE
}

// ---- phase 3: expand bits to f32 (proven) ----------------------------------
__global__ __launch_bounds__(256) void fmfm_expand(
    const uint32_t* __restrict__ bits,  // [T/32][B]
    float*          __restrict__ out)   // [T][B]
{
    const int tid = blockIdx.x * 256 + threadIdx.x;  // 0..131071
    const int b4  = tid & 1023;
    const int w   = tid >> 10;
    const uint4 wv = *reinterpret_cast<const uint4*>(
        bits + (size_t)w * B_NEUR + (size_t)b4 * 4);
    float4* o = reinterpret_cast<float4*>(
        out + (size_t)w * 32 * B_NEUR + (size_t)b4 * 4);
    #pragma unroll
    for (int j = 0; j < 32; ++j) {
        float4 v;
        v.x = ((wv.x >> j) & 1u) ? 1.0f : 0.0f;
        v.y = ((wv.y >> j) & 1u) ? 1.0f : 0.0f;
        v.z = ((wv.z >> j) & 1u) ? 1.0f : 0.0f;
        v.w = ((wv.w >> j) & 1u) ? 1.0f : 0.0f;
        o[(size_t)j * (B_NEUR / 4)] = v;
    }
}

// ---- fallback: round-1 proven fused kernel (if ws too small) ---------------
__global__ __launch_bounds__(64) void fmfm_scan_fused(
    const float2* __restrict__ sp, const float* __restrict__ W,
    float* __restrict__ out)
{
    const int b = blockIdx.x * 64 + threadIdx.x;
    const float w1 = W[0];
    const float w2 = W[1];
    const float2* p = sp + b;
    float* q = out + b;
    float mem = 0.0f, rst = 0.0f;
    #pragma unroll 8
    for (int t = 0; t < T_STEPS; ++t) {
        float2 s = p[(size_t)t * B_NEUR];
        float cur = __fadd_rn(__fmul_rn(s.x, w1), __fmul_rn(s.y, w2));
        float m = __fsub_rn(__fadd_rn(__fmul_rn(0.95f, mem), cur), rst);
        float spk = (m > 1.0f) ? 1.0f : 0.0f;
        q[(size_t)t * B_NEUR] = spk;
        mem = m;
        rst = spk;
    }
}

extern "C" void kernel_launch(void* const* d_in, const int* in_sizes, int n_in,
                              void* d_out, int out_size, void* d_ws, size_t ws_size,
                              hipStream_t stream) {
    const float2* sp  = (const float2*)d_in[0];
    const float*  W   = (const float*)d_in[1];
    float*        out = (float*)d_out;

    const size_t codes_bytes = (size_t)KG * B_NEUR * sizeof(uint32_t);     // 4MB
    const size_t bits_bytes  = (size_t)NWORDS * B_NEUR * sizeof(uint32_t); // 2MB
    if (ws_size < codes_bytes + bits_bytes) {
        fmfm_scan_fused<<<dim3(B_NEUR / 64), dim3(64), 0, stream>>>(sp, W, out);
        return;
    }
    uint32_t* codes = (uint32_t*)d_ws;
    uint32_t* bits  = (uint32_t*)((char*)d_ws + codes_bytes);

    fmfm_compress<<<dim3(KG * B_NEUR / 256), dim3(256), 0, stream>>>(sp, codes);
    fmfm_scan_codes<<<dim3(B_NEUR / 64), dim3(64), 0, stream>>>(codes, W, bits);
    fmfm_expand<<<dim3(NWORDS * (B_NEUR / 4) / 256), dim3(256), 0, stream>>>(bits, out);
}